// Round 18
// baseline (286.183 us; speedup 1.0000x reference)
//
#include <hip/hip_runtime.h>
#include <hip/hip_bf16.h>
#include <stdint.h>

// Problem sizes (fixed): N=8192 nodes, K=64 bins, DK=64, G=16 modes, TAU=1
#define NN 8192

typedef __attribute__((ext_vector_type(8))) __bf16 bf16x8;
typedef __attribute__((ext_vector_type(4))) __bf16 bf16x4;
typedef __attribute__((ext_vector_type(4))) float f32x4;

// ---- workspace layout (float offsets) ----
// [0] sumsqP [1] sumsqA  [64:128) colsumP  [128:192) colsumA
// [192:1216) k_g[16][64]
// byte 529408: PTF bf16 fragment-ordered [256 kb][4 ii][64 lane][8] (1 MB)
// [394496:427776) k1 partials: 256 x 130
// [427776:493312) k_g partials: 64 x 16 x 64
#define WS_KG    192
#define WS_PT_BYTE 529408
#define WS_PART  394496
#define WS_KGP   427776

// ---------------- Threefry-2x32, JAX-compatible (key = (0,42)) -------------
__device__ __forceinline__ void threefry2x32(uint32_t x0, uint32_t x1,
                                             uint32_t& o0, uint32_t& o1) {
  const uint32_t k0 = 0u, k1 = 42u;
  const uint32_t k2 = k0 ^ k1 ^ 0x1BD11BDAu;
  x0 += k0; x1 += k1;
#define TF_R(r) { x0 += x1; x1 = (x1 << (r)) | (x1 >> (32 - (r))); x1 ^= x0; }
  TF_R(13) TF_R(15) TF_R(26) TF_R(6)
  x0 += k1; x1 += k2 + 1u;
  TF_R(17) TF_R(29) TF_R(16) TF_R(24)
  x0 += k2; x1 += k0 + 2u;
  TF_R(13) TF_R(15) TF_R(26) TF_R(6)
  x0 += k0; x1 += k1 + 3u;
  TF_R(17) TF_R(29) TF_R(16) TF_R(24)
  x0 += k1; x1 += k2 + 4u;
  TF_R(13) TF_R(15) TF_R(26) TF_R(6)
  x0 += k2; x1 += k0 + 5u;
#undef TF_R
  o0 = x0; o1 = x1;
}

__device__ __forceinline__ bf16x8 cvt8(const float* __restrict__ p) {
  float4 a = *(const float4*)p;
  float4 b = *(const float4*)(p + 4);
  bf16x8 r;
  r[0] = (__bf16)a.x; r[1] = (__bf16)a.y; r[2] = (__bf16)a.z; r[3] = (__bf16)a.w;
  r[4] = (__bf16)b.x; r[5] = (__bf16)b.y; r[6] = (__bf16)b.z; r[7] = (__bf16)b.w;
  return r;
}

__device__ __forceinline__ bf16x8 cvt8g(const float* p) {  // generic/LDS
  float4 a = *(const float4*)p;
  float4 b = *(const float4*)(p + 4);
  bf16x8 r;
  r[0] = (__bf16)a.x; r[1] = (__bf16)a.y; r[2] = (__bf16)a.z; r[3] = (__bf16)a.w;
  r[4] = (__bf16)b.x; r[5] = (__bf16)b.y; r[6] = (__bf16)b.z; r[7] = (__bf16)b.w;
  return r;
}

__device__ __forceinline__ void st4bf(__bf16* p, float4 v) {
  bf16x4 b;
  b[0] = (__bf16)v.x; b[1] = (__bf16)v.y; b[2] = (__bf16)v.z; b[3] = (__bf16)v.w;
  *(bf16x4*)p = b;
}

// ---------------- K1: per-block partial colsums + sumsq (overwrite) --------
__global__ __launch_bounds__(256) void k1_partial(const float* __restrict__ Pin,
                                                  const float* __restrict__ Ain,
                                                  float* __restrict__ ws) {
  __shared__ float scp[64], sca[64], ssq[2];
  int t = threadIdx.x, b = blockIdx.x;
  if (t < 64) { scp[t] = 0.f; sca[t] = 0.f; }
  if (t < 2) ssq[t] = 0.f;
  __syncthreads();
  const float4* P4 = (const float4*)Pin;
  const float4* A4 = (const float4*)Ain;
  float sp = 0.f, sa = 0.f;
  float cp0 = 0, cp1 = 0, cp2 = 0, cp3 = 0, ca0 = 0, ca1 = 0, ca2 = 0, ca3 = 0;
  int base = b * 512 + t;
#pragma unroll
  for (int k = 0; k < 2; ++k) {
    float4 p = P4[base + k * 256], a = A4[base + k * 256];
    sp += p.x * p.x + p.y * p.y + p.z * p.z + p.w * p.w;
    sa += a.x * a.x + a.y * a.y + a.z * a.z + a.w * a.w;
    cp0 += p.x; cp1 += p.y; cp2 += p.z; cp3 += p.w;
    ca0 += a.x; ca1 += a.y; ca2 += a.z; ca3 += a.w;
  }
  int c0 = (t * 4) & 63;
  atomicAdd(&scp[c0 + 0], cp0); atomicAdd(&scp[c0 + 1], cp1);
  atomicAdd(&scp[c0 + 2], cp2); atomicAdd(&scp[c0 + 3], cp3);
  atomicAdd(&sca[c0 + 0], ca0); atomicAdd(&sca[c0 + 1], ca1);
  atomicAdd(&sca[c0 + 2], ca2); atomicAdd(&sca[c0 + 3], ca3);
  for (int off = 32; off; off >>= 1) {
    sp += __shfl_down(sp, off);
    sa += __shfl_down(sa, off);
  }
  if ((t & 63) == 0) { atomicAdd(&ssq[0], sp); atomicAdd(&ssq[1], sa); }
  __syncthreads();
  float* dst = ws + WS_PART + b * 130;
  if (t < 64) { dst[2 + t] = scp[t]; dst[66 + t] = sca[t]; }
  if (t == 0) { dst[0] = ssq[0]; dst[1] = ssq[1]; }
}

// ---------------- K2a: split-K partial k_g --------------------------------
__global__ __launch_bounds__(256) void k2a_kgpart(const float* __restrict__ Wsflat,
                                                  const float* __restrict__ Wkw,
                                                  float* __restrict__ ws) {
  __shared__ float wkT[64][65];   // [j][o]
  __shared__ float wsT[64][17];   // [j][g]
  int t = threadIdx.x, b = blockIdx.x;
  int c0 = b * 64;
  for (int idx = t; idx < 1024; idx += 256) {
    int o = idx >> 4, c4 = idx & 15;
    float4 v = *(const float4*)(Wkw + o * 4096 + c0 + c4 * 4);
    wkT[c4 * 4 + 0][o] = v.x; wkT[c4 * 4 + 1][o] = v.y;
    wkT[c4 * 4 + 2][o] = v.z; wkT[c4 * 4 + 3][o] = v.w;
  }
  {
    int g = t >> 4, c4 = t & 15;
    float4 v = *(const float4*)(Wsflat + g * 4096 + c0 + c4 * 4);
    wsT[c4 * 4 + 0][g] = v.x; wsT[c4 * 4 + 1][g] = v.y;
    wsT[c4 * 4 + 2][g] = v.z; wsT[c4 * 4 + 3][g] = v.w;
  }
  __syncthreads();
  int o = t & 63, g0 = (t >> 6) * 4;
  float a0 = 0.f, a1 = 0.f, a2 = 0.f, a3 = 0.f;
#pragma unroll 8
  for (int j = 0; j < 64; ++j) {
    float wk = wkT[j][o];
    a0 += wk * wsT[j][g0 + 0];
    a1 += wk * wsT[j][g0 + 1];
    a2 += wk * wsT[j][g0 + 2];
    a3 += wk * wsT[j][g0 + 3];
  }
  float* dst = ws + WS_KGP + b * 1024;
  dst[(g0 + 0) * 64 + o] = a0; dst[(g0 + 1) * 64 + o] = a1;
  dst[(g0 + 2) * 64 + o] = a2; dst[(g0 + 3) * 64 + o] = a3;
}

// ---------------- K2b: reduce k_g partials (blocks 0-15) + k1 fold (16) ----
__global__ __launch_bounds__(256) void k2b_reduce(const float* __restrict__ Wkb,
                                                  float* __restrict__ ws) {
  int g = blockIdx.x, t = threadIdx.x;
  if (g == 16) {
    if (t < 130) {
      float s = 0.f;
#pragma unroll 8
      for (int b = 0; b < 256; ++b) s += ws[WS_PART + b * 130 + t];
      if (t == 0) ws[0] = s;
      else if (t == 1) ws[1] = s;
      else if (t < 66) ws[64 + (t - 2)] = s;
      else ws[128 + (t - 66)] = s;
    }
    return;
  }
  __shared__ float red[4][64];
  int o = t & 63, bq = t >> 6;
  float s = 0.f;
#pragma unroll
  for (int b = bq * 16; b < bq * 16 + 16; ++b)
    s += ws[WS_KGP + b * 1024 + g * 64 + o];
  red[bq][o] = s;
  __syncthreads();
  if (bq == 0)
    ws[WS_KG + g * 64 + o] = red[0][o] + red[1][o] + red[2][o] + red[3][o] + Wkb[o];
}

// ---------------- K34: per-node pipeline + propagated einsum (fused) -------
// 256 blocks x 256 thr (4 waves); block owns nodes n0..n0+31 (8 per wave).
// Phase E writes PTF in FRAGMENT ORDER (coalesced consumption by k5):
//   PTF[kb][ii][lane][j] = propagated[kb*32+(lane>>4)*8+j][ii*16+(lane&15)]
__global__ __launch_bounds__(256) void k34_fused(
    const float* __restrict__ z, const float* __restrict__ Pref,
    const float* __restrict__ Aref,
    const float* __restrict__ Wind_w, const float* __restrict__ Wind_b,
    const float* __restrict__ Wgate_w, const float* __restrict__ Wgate_b,
    const float* __restrict__ Wsys_w, const float* __restrict__ Wsys_b,
    const float* __restrict__ Ws,
    const float* __restrict__ ws, float* __restrict__ out_s,
    __bf16* __restrict__ PTF) {
  int t = threadIdx.x, wv = t >> 6, lane = t & 63;
  int lg = lane >> 4, lm = lane & 15;
  int n0 = blockIdx.x * 32;
  int nb = n0 + wv * 8;
  __shared__ float qs[4][16][68];
  __shared__ float dpa[4][2][16];
  __shared__ float al_lds[32][16];
  {
    int nl = lane >> 3, qt = lane & 7;
    const float4* pr4 = (const float4*)(Pref + (nb + nl) * 64 + qt * 8);
    const float4* ar4 = (const float4*)(Aref + (nb + nl) * 64 + qt * 8);
    const float4* mp4 = (const float4*)(ws + 64 + qt * 8);
    const float4* ma4 = (const float4*)(ws + 128 + qt * 8);
    float s1p = 0, s2p = 0, s1a = 0, s2a = 0;
#pragma unroll
    for (int j = 0; j < 2; ++j) {
      float4 p = pr4[j], a = ar4[j], mp = mp4[j], ma = ma4[j];
      s1p += p.x * mp.x + p.y * mp.y + p.z * mp.z + p.w * mp.w;
      s2p += p.x * p.x + p.y * p.y + p.z * p.z + p.w * p.w;
      s1a += a.x * ma.x + a.y * ma.y + a.z * ma.z + a.w * ma.w;
      s2a += a.x * a.x + a.y * a.y + a.z * a.z + a.w * a.w;
    }
    s1p += __shfl_xor(s1p, 1); s1p += __shfl_xor(s1p, 2); s1p += __shfl_xor(s1p, 4);
    s2p += __shfl_xor(s2p, 1); s2p += __shfl_xor(s2p, 2); s2p += __shfl_xor(s2p, 4);
    s1a += __shfl_xor(s1a, 1); s1a += __shfl_xor(s1a, 2); s1a += __shfl_xor(s1a, 4);
    s2a += __shfl_xor(s2a, 1); s2a += __shfl_xor(s2a, 2); s2a += __shfl_xor(s2a, 4);
    float m2P = ws[0] * (1.0f / 524288.0f);
    float m2A = ws[1] * (1.0f / 524288.0f);
    float dP = m2P - s1p * (2.0f / (64.0f * 8192.0f)) + s2p * (1.0f / 64.0f);
    float dA = m2A - s1a * (2.0f / (64.0f * 8192.0f)) + s2a * (1.0f / 64.0f);
    if (qt == 0) { dpa[wv][0][nl] = dP; dpa[wv][1][nl] = dA; }
    if (qt == 1) { dpa[wv][0][8 + nl] = 0.f; dpa[wv][1][8 + nl] = 0.f; }
  }
  int zrow = nb + lm; if (zrow > 8191) zrow = 8191;
  bf16x8 az[2];
#pragma unroll
  for (int h = 0; h < 2; ++h)
    az[h] = cvt8(z + zrow * 64 + h * 32 + lg * 8);
  f32x4 accg[4], acci[4];
#pragma unroll
  for (int ii = 0; ii < 4; ++ii) {
    f32x4 cg = {0.f, 0.f, 0.f, 0.f}, ci = {0.f, 0.f, 0.f, 0.f};
#pragma unroll
    for (int h = 0; h < 2; ++h) {
      bf16x8 bg = cvt8(Wgate_w + (ii * 16 + lm) * 64 + h * 32 + lg * 8);
      bf16x8 bi = cvt8(Wind_w + (ii * 16 + lm) * 64 + h * 32 + lg * 8);
      cg = __builtin_amdgcn_mfma_f32_16x16x32_bf16(az[h], bg, cg, 0, 0, 0);
      ci = __builtin_amdgcn_mfma_f32_16x16x32_bf16(az[h], bi, ci, 0, 0, 0);
    }
    accg[ii] = cg; acci[ii] = ci;
  }
  __syncthreads();
#pragma unroll
  for (int ii = 0; ii < 4; ++ii) {
    int o = ii * 16 + lm;
    float bg = Wgate_b[o], bi = Wind_b[o], bs = Wsys_b[o];
    float w0 = Wsys_w[o * 2], w1 = Wsys_w[o * 2 + 1];
#pragma unroll
    for (int r = 0; r < 4; ++r) {
      int node = lg * 4 + r;
      float dP = dpa[wv][0][node], dA = dpa[wv][1][node];
      float gate = 1.0f / (1.0f + expf(-(accg[ii][r] + bg)));
      float sys = dA * w0 + dP * w1 + bs;
      qs[wv][node][o] = acci[ii][r] + bi + gate * sys;
    }
  }
  __syncthreads();
  {
    bf16x8 aq[2], bq[2];
#pragma unroll
    for (int h = 0; h < 2; ++h) {
      aq[h] = cvt8g(&qs[wv][lm][h * 32 + lg * 8]);
      bq[h] = cvt8g(ws + WS_KG + lm * 64 + h * 32 + lg * 8);
    }
    f32x4 accs = {0.f, 0.f, 0.f, 0.f};
    accs = __builtin_amdgcn_mfma_f32_16x16x32_bf16(aq[0], bq[0], accs, 0, 0, 0);
    accs = __builtin_amdgcn_mfma_f32_16x16x32_bf16(aq[1], bq[1], accs, 0, 0, 0);
    if (lg < 2) {
#pragma unroll
      for (int r = 0; r < 4; ++r) {
        int n = nb + lg * 4 + r;
        float sv = accs[r] * 0.125f;
        uint32_t idx = (uint32_t)(n * 16 + lm);
        uint32_t r0_, r1_;
        threefry2x32(0u, idx, r0_, r1_);
        uint32_t bits = r0_ ^ r1_;
        float u = __uint_as_float((bits >> 9) | 0x3f800000u) - 1.0f;
        float gum = -logf(-logf(u + 1e-10f) + 1e-10f);
        float tv = sv + gum;  // TAU = 1
        float mx = tv;
        mx = fmaxf(mx, __shfl_xor(mx, 1)); mx = fmaxf(mx, __shfl_xor(mx, 2));
        mx = fmaxf(mx, __shfl_xor(mx, 4)); mx = fmaxf(mx, __shfl_xor(mx, 8));
        float e = expf(tv - mx);
        float se = e;
        se += __shfl_xor(se, 1); se += __shfl_xor(se, 2);
        se += __shfl_xor(se, 4); se += __shfl_xor(se, 8);
        out_s[n * 16 + lm] = sv;
        al_lds[wv * 8 + lg * 4 + r][lm] = e / se;
      }
    }
  }
  __syncthreads();
  bf16x8 af[2][2];
#pragma unroll
  for (int m = 0; m < 2; ++m)
#pragma unroll
    for (int h = 0; h < 2; ++h)
      af[m][h] = cvt8(z + (n0 + m * 16 + lm) * 64 + h * 32 + lg * 8);
  int i0 = wv * 16;
  f32x4 prop[2] = {{0.f, 0.f, 0.f, 0.f}, {0.f, 0.f, 0.f, 0.f}};
  for (int g = 0; g < 16; ++g) {
    bf16x8 bf[2];
#pragma unroll
    for (int h = 0; h < 2; ++h)
      bf[h] = cvt8(Ws + g * 4096 + (i0 + lm) * 64 + h * 32 + lg * 8);
#pragma unroll
    for (int m = 0; m < 2; ++m) {
      f32x4 tf = {0.f, 0.f, 0.f, 0.f};
      tf = __builtin_amdgcn_mfma_f32_16x16x32_bf16(af[m][0], bf[0], tf, 0, 0, 0);
      tf = __builtin_amdgcn_mfma_f32_16x16x32_bf16(af[m][1], bf[1], tf, 0, 0, 0);
#pragma unroll
      for (int r = 0; r < 4; ++r)
        prop[m][r] += al_lds[m * 16 + lg * 4 + r][g] * tf[r];
    }
  }
  // PTF write: flat = blk*2048 + wv*512 + (m*2+(lg>>1))*128 + lm*8 + (lg&1)*4 + r
#pragma unroll
  for (int m = 0; m < 2; ++m) {
    float4 v = {prop[m][0], prop[m][1], prop[m][2], prop[m][3]};
    st4bf(PTF + blockIdx.x * 2048 + wv * 512 + (m * 2 + (lg >> 1)) * 128 +
              lm * 8 + (lg & 1) * 4, v);
  }
}

// ---------------- K5: h = leaky_relu(R @ propagated), coalesced B ----------
__global__ __launch_bounds__(512) void k5_gemm(const float* __restrict__ R,
                                               const __bf16* __restrict__ PTF,
                                               float* __restrict__ out) {
  __shared__ __bf16 lds[2][16][520];   // 33.3 KB
  int t = threadIdx.x, wv = t >> 6, lane = t & 63;
  int lg = lane >> 4, lm = lane & 15;
  int row0 = blockIdx.x * 16;
  int srow[4], scol[4];
#pragma unroll
  for (int r = 0; r < 4; ++r) {
    int idx = r * 512 + t;
    srow[r] = idx >> 7;
    scol[r] = (idx & 127) * 4;
  }
  const float* Rb = R + (size_t)row0 * 8192;
  f32x4 acc[4];
#pragma unroll
  for (int ii = 0; ii < 4; ++ii) acc[ii] = {0.f, 0.f, 0.f, 0.f};
  float4 stg[4];
#pragma unroll
  for (int r = 0; r < 4; ++r)
    stg[r] = *(const float4*)(Rb + (size_t)srow[r] * 8192 + scol[r]);
#pragma unroll
  for (int r = 0; r < 4; ++r)
    st4bf(&lds[0][srow[r]][scol[r]], stg[r]);
  __syncthreads();
  for (int tile = 0; tile < 16; ++tile) {
    int cur = tile & 1;
    if (tile < 15) {
#pragma unroll
      for (int r = 0; r < 4; ++r)
        stg[r] = *(const float4*)(Rb + (size_t)srow[r] * 8192 + (tile + 1) * 512 + scol[r]);
    }
#pragma unroll
    for (int ks = 0; ks < 2; ++ks) {
      int kc = wv * 64 + ks * 32 + lg * 8;
      bf16x8 a = *(const bf16x8*)&lds[cur][lm][kc];
      int kb = tile * 16 + wv * 2 + ks;
#pragma unroll
      for (int ii = 0; ii < 4; ++ii) {
        bf16x8 b = *(const bf16x8*)(PTF + kb * 2048 + ii * 512 + lane * 8);
        acc[ii] = __builtin_amdgcn_mfma_f32_16x16x32_bf16(a, b, acc[ii], 0, 0, 0);
      }
    }
    if (tile < 15) {
#pragma unroll
      for (int r = 0; r < 4; ++r)
        st4bf(&lds[cur ^ 1][srow[r]][scol[r]], stg[r]);
    }
    __syncthreads();
  }
  float* red = (float*)&lds[0][0][0];
#pragma unroll
  for (int ii = 0; ii < 4; ++ii)
#pragma unroll
    for (int r = 0; r < 4; ++r)
      red[wv * 1024 + (lg * 4 + r) * 64 + ii * 16 + lm] = acc[ii][r];
  __syncthreads();
  for (int e = t; e < 1024; e += 512) {
    int rr = e >> 6, cc = e & 63;
    float v = 0.f;
#pragma unroll
    for (int w = 0; w < 8; ++w) v += red[w * 1024 + rr * 64 + cc];
    v = v > 0.f ? v : 0.01f * v;
    out[(row0 + rr) * 64 + cc] = v;
  }
}

extern "C" void kernel_launch(void* const* d_in, const int* in_sizes, int n_in,
                              void* d_out, int out_size, void* d_ws, size_t ws_size,
                              hipStream_t stream) {
  const float* z      = (const float*)d_in[0];
  const float* Pref   = (const float*)d_in[1];
  const float* Pin    = (const float*)d_in[2];
  const float* Aref   = (const float*)d_in[3];
  const float* Ain    = (const float*)d_in[4];
  const float* R      = (const float*)d_in[5];
  const float* Wind_w = (const float*)d_in[6];
  const float* Wind_b = (const float*)d_in[7];
  const float* Wgate_w= (const float*)d_in[8];
  const float* Wgate_b= (const float*)d_in[9];
  const float* Wsys_w = (const float*)d_in[10];
  const float* Wsys_b = (const float*)d_in[11];
  const float* Ws     = (const float*)d_in[12];
  const float* Wkw    = (const float*)d_in[13];
  const float* Wkb    = (const float*)d_in[14];
  float* out = (float*)d_out;
  float* ws  = (float*)d_ws;
  __bf16* PTF = (__bf16*)((char*)d_ws + WS_PT_BYTE);

  k1_partial<<<256, 256, 0, stream>>>(Pin, Ain, ws);
  k2a_kgpart<<<64, 256, 0, stream>>>(Ws, Wkw, ws);
  k2b_reduce<<<17, 256, 0, stream>>>(Wkb, ws);
  k34_fused<<<256, 256, 0, stream>>>(z, Pref, Aref, Wind_w, Wind_b, Wgate_w,
                                     Wgate_b, Wsys_w, Wsys_b, Ws, ws,
                                     out + 524288, PTF);
  // PROBE: k5 x4 (idempotent). k5_time = (dur - 109.3)/3
  k5_gemm<<<512, 512, 0, stream>>>(R, PTF, out);
  k5_gemm<<<512, 512, 0, stream>>>(R, PTF, out);
  k5_gemm<<<512, 512, 0, stream>>>(R, PTF, out);
  k5_gemm<<<512, 512, 0, stream>>>(R, PTF, out);
}

// Round 19
// 109.206 us; speedup vs baseline: 2.6206x; 2.6206x over previous
//
#include <hip/hip_runtime.h>
#include <hip/hip_bf16.h>
#include <stdint.h>

// Problem sizes (fixed): N=8192 nodes, K=64 bins, DK=64, G=16 modes, TAU=1
#define NN 8192

typedef __attribute__((ext_vector_type(8))) __bf16 bf16x8;
typedef __attribute__((ext_vector_type(4))) __bf16 bf16x4;
typedef __attribute__((ext_vector_type(4))) float f32x4;

// ---- workspace layout (float offsets) ----
// [0] sumsqP [1] sumsqA  [64:128) colsumP  [128:192) colsumA
// [192:1216) k_g[16][64]
// byte 529408: PTF bf16 fragment-ordered [256 kb][4 ii][64 lane][8] (1 MB)
// [394496:427776) k1 partials: 256 x 130
// [427776:493312) k_g partials: 64 x 16 x 64
#define WS_KG    192
#define WS_PT_BYTE 529408
#define WS_PART  394496
#define WS_KGP   427776

// ---------------- Threefry-2x32, JAX-compatible (key = (0,42)) -------------
__device__ __forceinline__ void threefry2x32(uint32_t x0, uint32_t x1,
                                             uint32_t& o0, uint32_t& o1) {
  const uint32_t k0 = 0u, k1 = 42u;
  const uint32_t k2 = k0 ^ k1 ^ 0x1BD11BDAu;
  x0 += k0; x1 += k1;
#define TF_R(r) { x0 += x1; x1 = (x1 << (r)) | (x1 >> (32 - (r))); x1 ^= x0; }
  TF_R(13) TF_R(15) TF_R(26) TF_R(6)
  x0 += k1; x1 += k2 + 1u;
  TF_R(17) TF_R(29) TF_R(16) TF_R(24)
  x0 += k2; x1 += k0 + 2u;
  TF_R(13) TF_R(15) TF_R(26) TF_R(6)
  x0 += k0; x1 += k1 + 3u;
  TF_R(17) TF_R(29) TF_R(16) TF_R(24)
  x0 += k1; x1 += k2 + 4u;
  TF_R(13) TF_R(15) TF_R(26) TF_R(6)
  x0 += k2; x1 += k0 + 5u;
#undef TF_R
  o0 = x0; o1 = x1;
}

__device__ __forceinline__ bf16x8 cvt8(const float* __restrict__ p) {
  float4 a = *(const float4*)p;
  float4 b = *(const float4*)(p + 4);
  bf16x8 r;
  r[0] = (__bf16)a.x; r[1] = (__bf16)a.y; r[2] = (__bf16)a.z; r[3] = (__bf16)a.w;
  r[4] = (__bf16)b.x; r[5] = (__bf16)b.y; r[6] = (__bf16)b.z; r[7] = (__bf16)b.w;
  return r;
}

__device__ __forceinline__ bf16x8 cvt8g(const float* p) {  // generic/LDS
  float4 a = *(const float4*)p;
  float4 b = *(const float4*)(p + 4);
  bf16x8 r;
  r[0] = (__bf16)a.x; r[1] = (__bf16)a.y; r[2] = (__bf16)a.z; r[3] = (__bf16)a.w;
  r[4] = (__bf16)b.x; r[5] = (__bf16)b.y; r[6] = (__bf16)b.z; r[7] = (__bf16)b.w;
  return r;
}

__device__ __forceinline__ void st4bf(__bf16* p, float4 v) {
  bf16x4 b;
  b[0] = (__bf16)v.x; b[1] = (__bf16)v.y; b[2] = (__bf16)v.z; b[3] = (__bf16)v.w;
  *(bf16x4*)p = b;
}

// ---------------- K1: per-block partial colsums + sumsq (overwrite) --------
__global__ __launch_bounds__(256) void k1_partial(const float* __restrict__ Pin,
                                                  const float* __restrict__ Ain,
                                                  float* __restrict__ ws) {
  __shared__ float scp[64], sca[64], ssq[2];
  int t = threadIdx.x, b = blockIdx.x;
  if (t < 64) { scp[t] = 0.f; sca[t] = 0.f; }
  if (t < 2) ssq[t] = 0.f;
  __syncthreads();
  const float4* P4 = (const float4*)Pin;
  const float4* A4 = (const float4*)Ain;
  float sp = 0.f, sa = 0.f;
  float cp0 = 0, cp1 = 0, cp2 = 0, cp3 = 0, ca0 = 0, ca1 = 0, ca2 = 0, ca3 = 0;
  int base = b * 512 + t;
#pragma unroll
  for (int k = 0; k < 2; ++k) {
    float4 p = P4[base + k * 256], a = A4[base + k * 256];
    sp += p.x * p.x + p.y * p.y + p.z * p.z + p.w * p.w;
    sa += a.x * a.x + a.y * a.y + a.z * a.z + a.w * a.w;
    cp0 += p.x; cp1 += p.y; cp2 += p.z; cp3 += p.w;
    ca0 += a.x; ca1 += a.y; ca2 += a.z; ca3 += a.w;
  }
  int c0 = (t * 4) & 63;
  atomicAdd(&scp[c0 + 0], cp0); atomicAdd(&scp[c0 + 1], cp1);
  atomicAdd(&scp[c0 + 2], cp2); atomicAdd(&scp[c0 + 3], cp3);
  atomicAdd(&sca[c0 + 0], ca0); atomicAdd(&sca[c0 + 1], ca1);
  atomicAdd(&sca[c0 + 2], ca2); atomicAdd(&sca[c0 + 3], ca3);
  for (int off = 32; off; off >>= 1) {
    sp += __shfl_down(sp, off);
    sa += __shfl_down(sa, off);
  }
  if ((t & 63) == 0) { atomicAdd(&ssq[0], sp); atomicAdd(&ssq[1], sa); }
  __syncthreads();
  float* dst = ws + WS_PART + b * 130;
  if (t < 64) { dst[2 + t] = scp[t]; dst[66 + t] = sca[t]; }
  if (t == 0) { dst[0] = ssq[0]; dst[1] = ssq[1]; }
}

// ---------------- K2a: split-K partial k_g --------------------------------
__global__ __launch_bounds__(256) void k2a_kgpart(const float* __restrict__ Wsflat,
                                                  const float* __restrict__ Wkw,
                                                  float* __restrict__ ws) {
  __shared__ float wkT[64][65];   // [j][o]
  __shared__ float wsT[64][17];   // [j][g]
  int t = threadIdx.x, b = blockIdx.x;
  int c0 = b * 64;
  for (int idx = t; idx < 1024; idx += 256) {
    int o = idx >> 4, c4 = idx & 15;
    float4 v = *(const float4*)(Wkw + o * 4096 + c0 + c4 * 4);
    wkT[c4 * 4 + 0][o] = v.x; wkT[c4 * 4 + 1][o] = v.y;
    wkT[c4 * 4 + 2][o] = v.z; wkT[c4 * 4 + 3][o] = v.w;
  }
  {
    int g = t >> 4, c4 = t & 15;
    float4 v = *(const float4*)(Wsflat + g * 4096 + c0 + c4 * 4);
    wsT[c4 * 4 + 0][g] = v.x; wsT[c4 * 4 + 1][g] = v.y;
    wsT[c4 * 4 + 2][g] = v.z; wsT[c4 * 4 + 3][g] = v.w;
  }
  __syncthreads();
  int o = t & 63, g0 = (t >> 6) * 4;
  float a0 = 0.f, a1 = 0.f, a2 = 0.f, a3 = 0.f;
#pragma unroll 8
  for (int j = 0; j < 64; ++j) {
    float wk = wkT[j][o];
    a0 += wk * wsT[j][g0 + 0];
    a1 += wk * wsT[j][g0 + 1];
    a2 += wk * wsT[j][g0 + 2];
    a3 += wk * wsT[j][g0 + 3];
  }
  float* dst = ws + WS_KGP + b * 1024;
  dst[(g0 + 0) * 64 + o] = a0; dst[(g0 + 1) * 64 + o] = a1;
  dst[(g0 + 2) * 64 + o] = a2; dst[(g0 + 3) * 64 + o] = a3;
}

// ---------------- K2b: reduce k_g partials (blocks 0-15) + k1 fold (16) ----
__global__ __launch_bounds__(256) void k2b_reduce(const float* __restrict__ Wkb,
                                                  float* __restrict__ ws) {
  int g = blockIdx.x, t = threadIdx.x;
  if (g == 16) {
    if (t < 130) {
      float s = 0.f;
#pragma unroll 8
      for (int b = 0; b < 256; ++b) s += ws[WS_PART + b * 130 + t];
      if (t == 0) ws[0] = s;
      else if (t == 1) ws[1] = s;
      else if (t < 66) ws[64 + (t - 2)] = s;
      else ws[128 + (t - 66)] = s;
    }
    return;
  }
  __shared__ float red[4][64];
  int o = t & 63, bq = t >> 6;
  float s = 0.f;
#pragma unroll
  for (int b = bq * 16; b < bq * 16 + 16; ++b)
    s += ws[WS_KGP + b * 1024 + g * 64 + o];
  red[bq][o] = s;
  __syncthreads();
  if (bq == 0)
    ws[WS_KG + g * 64 + o] = red[0][o] + red[1][o] + red[2][o] + red[3][o] + Wkb[o];
}

// ---------------- K34: per-node pipeline + propagated einsum (fused) -------
__global__ __launch_bounds__(256) void k34_fused(
    const float* __restrict__ z, const float* __restrict__ Pref,
    const float* __restrict__ Aref,
    const float* __restrict__ Wind_w, const float* __restrict__ Wind_b,
    const float* __restrict__ Wgate_w, const float* __restrict__ Wgate_b,
    const float* __restrict__ Wsys_w, const float* __restrict__ Wsys_b,
    const float* __restrict__ Ws,
    const float* __restrict__ ws, float* __restrict__ out_s,
    __bf16* __restrict__ PTF) {
  int t = threadIdx.x, wv = t >> 6, lane = t & 63;
  int lg = lane >> 4, lm = lane & 15;
  int n0 = blockIdx.x * 32;
  int nb = n0 + wv * 8;
  __shared__ float qs[4][16][68];
  __shared__ float dpa[4][2][16];
  __shared__ float al_lds[32][16];
  {
    int nl = lane >> 3, qt = lane & 7;
    const float4* pr4 = (const float4*)(Pref + (nb + nl) * 64 + qt * 8);
    const float4* ar4 = (const float4*)(Aref + (nb + nl) * 64 + qt * 8);
    const float4* mp4 = (const float4*)(ws + 64 + qt * 8);
    const float4* ma4 = (const float4*)(ws + 128 + qt * 8);
    float s1p = 0, s2p = 0, s1a = 0, s2a = 0;
#pragma unroll
    for (int j = 0; j < 2; ++j) {
      float4 p = pr4[j], a = ar4[j], mp = mp4[j], ma = ma4[j];
      s1p += p.x * mp.x + p.y * mp.y + p.z * mp.z + p.w * mp.w;
      s2p += p.x * p.x + p.y * p.y + p.z * p.z + p.w * p.w;
      s1a += a.x * ma.x + a.y * ma.y + a.z * ma.z + a.w * ma.w;
      s2a += a.x * a.x + a.y * a.y + a.z * a.z + a.w * a.w;
    }
    s1p += __shfl_xor(s1p, 1); s1p += __shfl_xor(s1p, 2); s1p += __shfl_xor(s1p, 4);
    s2p += __shfl_xor(s2p, 1); s2p += __shfl_xor(s2p, 2); s2p += __shfl_xor(s2p, 4);
    s1a += __shfl_xor(s1a, 1); s1a += __shfl_xor(s1a, 2); s1a += __shfl_xor(s1a, 4);
    s2a += __shfl_xor(s2a, 1); s2a += __shfl_xor(s2a, 2); s2a += __shfl_xor(s2a, 4);
    float m2P = ws[0] * (1.0f / 524288.0f);
    float m2A = ws[1] * (1.0f / 524288.0f);
    float dP = m2P - s1p * (2.0f / (64.0f * 8192.0f)) + s2p * (1.0f / 64.0f);
    float dA = m2A - s1a * (2.0f / (64.0f * 8192.0f)) + s2a * (1.0f / 64.0f);
    if (qt == 0) { dpa[wv][0][nl] = dP; dpa[wv][1][nl] = dA; }
    if (qt == 1) { dpa[wv][0][8 + nl] = 0.f; dpa[wv][1][8 + nl] = 0.f; }
  }
  int zrow = nb + lm; if (zrow > 8191) zrow = 8191;
  bf16x8 az[2];
#pragma unroll
  for (int h = 0; h < 2; ++h)
    az[h] = cvt8(z + zrow * 64 + h * 32 + lg * 8);
  f32x4 accg[4], acci[4];
#pragma unroll
  for (int ii = 0; ii < 4; ++ii) {
    f32x4 cg = {0.f, 0.f, 0.f, 0.f}, ci = {0.f, 0.f, 0.f, 0.f};
#pragma unroll
    for (int h = 0; h < 2; ++h) {
      bf16x8 bg = cvt8(Wgate_w + (ii * 16 + lm) * 64 + h * 32 + lg * 8);
      bf16x8 bi = cvt8(Wind_w + (ii * 16 + lm) * 64 + h * 32 + lg * 8);
      cg = __builtin_amdgcn_mfma_f32_16x16x32_bf16(az[h], bg, cg, 0, 0, 0);
      ci = __builtin_amdgcn_mfma_f32_16x16x32_bf16(az[h], bi, ci, 0, 0, 0);
    }
    accg[ii] = cg; acci[ii] = ci;
  }
  __syncthreads();
#pragma unroll
  for (int ii = 0; ii < 4; ++ii) {
    int o = ii * 16 + lm;
    float bg = Wgate_b[o], bi = Wind_b[o], bs = Wsys_b[o];
    float w0 = Wsys_w[o * 2], w1 = Wsys_w[o * 2 + 1];
#pragma unroll
    for (int r = 0; r < 4; ++r) {
      int node = lg * 4 + r;
      float dP = dpa[wv][0][node], dA = dpa[wv][1][node];
      float gate = 1.0f / (1.0f + expf(-(accg[ii][r] + bg)));
      float sys = dA * w0 + dP * w1 + bs;
      qs[wv][node][o] = acci[ii][r] + bi + gate * sys;
    }
  }
  __syncthreads();
  {
    bf16x8 aq[2], bq[2];
#pragma unroll
    for (int h = 0; h < 2; ++h) {
      aq[h] = cvt8g(&qs[wv][lm][h * 32 + lg * 8]);
      bq[h] = cvt8g(ws + WS_KG + lm * 64 + h * 32 + lg * 8);
    }
    f32x4 accs = {0.f, 0.f, 0.f, 0.f};
    accs = __builtin_amdgcn_mfma_f32_16x16x32_bf16(aq[0], bq[0], accs, 0, 0, 0);
    accs = __builtin_amdgcn_mfma_f32_16x16x32_bf16(aq[1], bq[1], accs, 0, 0, 0);
    if (lg < 2) {
#pragma unroll
      for (int r = 0; r < 4; ++r) {
        int n = nb + lg * 4 + r;
        float sv = accs[r] * 0.125f;
        uint32_t idx = (uint32_t)(n * 16 + lm);
        uint32_t r0_, r1_;
        threefry2x32(0u, idx, r0_, r1_);
        uint32_t bits = r0_ ^ r1_;
        float u = __uint_as_float((bits >> 9) | 0x3f800000u) - 1.0f;
        float gum = -logf(-logf(u + 1e-10f) + 1e-10f);
        float tv = sv + gum;  // TAU = 1
        float mx = tv;
        mx = fmaxf(mx, __shfl_xor(mx, 1)); mx = fmaxf(mx, __shfl_xor(mx, 2));
        mx = fmaxf(mx, __shfl_xor(mx, 4)); mx = fmaxf(mx, __shfl_xor(mx, 8));
        float e = expf(tv - mx);
        float se = e;
        se += __shfl_xor(se, 1); se += __shfl_xor(se, 2);
        se += __shfl_xor(se, 4); se += __shfl_xor(se, 8);
        out_s[n * 16 + lm] = sv;
        al_lds[wv * 8 + lg * 4 + r][lm] = e / se;
      }
    }
  }
  __syncthreads();
  bf16x8 af[2][2];
#pragma unroll
  for (int m = 0; m < 2; ++m)
#pragma unroll
    for (int h = 0; h < 2; ++h)
      af[m][h] = cvt8(z + (n0 + m * 16 + lm) * 64 + h * 32 + lg * 8);
  int i0 = wv * 16;
  f32x4 prop[2] = {{0.f, 0.f, 0.f, 0.f}, {0.f, 0.f, 0.f, 0.f}};
  for (int g = 0; g < 16; ++g) {
    bf16x8 bf[2];
#pragma unroll
    for (int h = 0; h < 2; ++h)
      bf[h] = cvt8(Ws + g * 4096 + (i0 + lm) * 64 + h * 32 + lg * 8);
#pragma unroll
    for (int m = 0; m < 2; ++m) {
      f32x4 tf = {0.f, 0.f, 0.f, 0.f};
      tf = __builtin_amdgcn_mfma_f32_16x16x32_bf16(af[m][0], bf[0], tf, 0, 0, 0);
      tf = __builtin_amdgcn_mfma_f32_16x16x32_bf16(af[m][1], bf[1], tf, 0, 0, 0);
#pragma unroll
      for (int r = 0; r < 4; ++r)
        prop[m][r] += al_lds[m * 16 + lg * 4 + r][g] * tf[r];
    }
  }
  // PTF write: flat = blk*2048 + wv*512 + (m*2+(lg>>1))*128 + lm*8 + (lg&1)*4 + r
#pragma unroll
  for (int m = 0; m < 2; ++m) {
    float4 v = {prop[m][0], prop[m][1], prop[m][2], prop[m][3]};
    st4bf(PTF + blockIdx.x * 2048 + wv * 512 + (m * 2 + (lg >> 1)) * 128 +
              lm * 8 + (lg & 1) * 4, v);
  }
}

// ---------------- K5: h = leaky_relu(R @ propagated), 2-deep prefetch ------
// 512 blocks x 512 thr; 16 rows/block; 16 K-tiles of 512 cols; bf16 LDS dbuf.
// TWO register staging sets, prefetch distance 2: the store of tile t+1's
// registers waits only on ITS loads (compiler emits vmcnt(4)), leaving tile
// t+2's 4 loads in flight ACROSS the barrier -- the HBM queue never drains
// (T4 counted-vmcnt, plain-HIP form). Tile loop fully unrolled so stg
// indices are compile-time (no scratch).
__global__ __launch_bounds__(512) void k5_gemm(const float* __restrict__ R,
                                               const __bf16* __restrict__ PTF,
                                               float* __restrict__ out) {
  __shared__ __bf16 lds[2][16][520];   // 33.3 KB
  int t = threadIdx.x, wv = t >> 6, lane = t & 63;
  int lg = lane >> 4, lm = lane & 15;
  int row0 = blockIdx.x * 16;
  int srow[4], scol[4];
#pragma unroll
  for (int r = 0; r < 4; ++r) {
    int idx = r * 512 + t;
    srow[r] = idx >> 7;
    scol[r] = (idx & 127) * 4;
  }
  const float* Rb = R + (size_t)row0 * 8192;
  f32x4 acc[4];
#pragma unroll
  for (int ii = 0; ii < 4; ++ii) acc[ii] = {0.f, 0.f, 0.f, 0.f};
  float4 stg[2][4];
  // prologue: T0 -> buf0 (direct), T1 loads issued into stg[1]
#pragma unroll
  for (int r = 0; r < 4; ++r)
    stg[0][r] = *(const float4*)(Rb + (size_t)srow[r] * 8192 + scol[r]);
#pragma unroll
  for (int r = 0; r < 4; ++r)
    st4bf(&lds[0][srow[r]][scol[r]], stg[0][r]);
#pragma unroll
  for (int r = 0; r < 4; ++r)
    stg[1][r] = *(const float4*)(Rb + (size_t)srow[r] * 8192 + 512 + scol[r]);
  __syncthreads();
#pragma unroll
  for (int tile = 0; tile < 16; ++tile) {
    int cur = tile & 1;
    // issue loads for tile+2 into the just-freed register set
    if (tile < 14) {
#pragma unroll
      for (int r = 0; r < 4; ++r)
        stg[tile & 1][r] =
            *(const float4*)(Rb + (size_t)srow[r] * 8192 + (tile + 2) * 512 + scol[r]);
    }
#pragma unroll
    for (int ks = 0; ks < 2; ++ks) {
      int kc = wv * 64 + ks * 32 + lg * 8;
      bf16x8 a = *(const bf16x8*)&lds[cur][lm][kc];
      int kb = tile * 16 + wv * 2 + ks;
#pragma unroll
      for (int ii = 0; ii < 4; ++ii) {
        bf16x8 b = *(const bf16x8*)(PTF + kb * 2048 + ii * 512 + lane * 8);
        acc[ii] = __builtin_amdgcn_mfma_f32_16x16x32_bf16(a, b, acc[ii], 0, 0, 0);
      }
    }
    // store tile+1's registers (waits vmcnt(4): only ITS loads; t+2 in flight)
    if (tile < 15) {
#pragma unroll
      for (int r = 0; r < 4; ++r)
        st4bf(&lds[cur ^ 1][srow[r]][scol[r]], stg[(tile + 1) & 1][r]);
    }
    __syncthreads();
  }
  // epilogue: reduce 8 waves' partial K-sums in LDS (reuse buffers; 32 KB)
  float* red = (float*)&lds[0][0][0];
#pragma unroll
  for (int ii = 0; ii < 4; ++ii)
#pragma unroll
    for (int r = 0; r < 4; ++r)
      red[wv * 1024 + (lg * 4 + r) * 64 + ii * 16 + lm] = acc[ii][r];
  __syncthreads();
  for (int e = t; e < 1024; e += 512) {
    int rr = e >> 6, cc = e & 63;
    float v = 0.f;
#pragma unroll
    for (int w = 0; w < 8; ++w) v += red[w * 1024 + rr * 64 + cc];
    v = v > 0.f ? v : 0.01f * v;
    out[(row0 + rr) * 64 + cc] = v;
  }
}

extern "C" void kernel_launch(void* const* d_in, const int* in_sizes, int n_in,
                              void* d_out, int out_size, void* d_ws, size_t ws_size,
                              hipStream_t stream) {
  const float* z      = (const float*)d_in[0];
  const float* Pref   = (const float*)d_in[1];
  const float* Pin    = (const float*)d_in[2];
  const float* Aref   = (const float*)d_in[3];
  const float* Ain    = (const float*)d_in[4];
  const float* R      = (const float*)d_in[5];
  const float* Wind_w = (const float*)d_in[6];
  const float* Wind_b = (const float*)d_in[7];
  const float* Wgate_w= (const float*)d_in[8];
  const float* Wgate_b= (const float*)d_in[9];
  const float* Wsys_w = (const float*)d_in[10];
  const float* Wsys_b = (const float*)d_in[11];
  const float* Ws     = (const float*)d_in[12];
  const float* Wkw    = (const float*)d_in[13];
  const float* Wkb    = (const float*)d_in[14];
  float* out = (float*)d_out;
  float* ws  = (float*)d_ws;
  __bf16* PTF = (__bf16*)((char*)d_ws + WS_PT_BYTE);

  k1_partial<<<256, 256, 0, stream>>>(Pin, Ain, ws);
  k2a_kgpart<<<64, 256, 0, stream>>>(Ws, Wkw, ws);
  k2b_reduce<<<17, 256, 0, stream>>>(Wkb, ws);
  k34_fused<<<256, 256, 0, stream>>>(z, Pref, Aref, Wind_w, Wind_b, Wgate_w,
                                     Wgate_b, Wsys_w, Wsys_b, Ws, ws,
                                     out + 524288, PTF);
  k5_gemm<<<512, 512, 0, stream>>>(R, PTF, out);
}

// Round 20
// 109.031 us; speedup vs baseline: 2.6248x; 1.0016x over previous
//
#include <hip/hip_runtime.h>
#include <hip/hip_bf16.h>
#include <stdint.h>

// Problem sizes (fixed): N=8192 nodes, K=64 bins, DK=64, G=16 modes, TAU=1
#define NN 8192

typedef __attribute__((ext_vector_type(8))) __bf16 bf16x8;
typedef __attribute__((ext_vector_type(4))) __bf16 bf16x4;
typedef __attribute__((ext_vector_type(4))) float f32x4;

// ---- workspace layout (float offsets) ----
// [0] sumsqP [1] sumsqA  [64:128) colsumP  [128:192) colsumA
// [192:1216) k_g[16][64]
// byte 529408: PTF bf16 fragment-ordered [256 kb][4 ii][64 lane][8] (1 MB)
// [394496:427776) k1 partials: 256 x 130
// [427776:493312) k_g partials: 64 x 16 x 64
#define WS_KG    192
#define WS_PT_BYTE 529408
#define WS_PART  394496
#define WS_KGP   427776

// ---------------- Threefry-2x32, JAX-compatible (key = (0,42)) -------------
__device__ __forceinline__ void threefry2x32(uint32_t x0, uint32_t x1,
                                             uint32_t& o0, uint32_t& o1) {
  const uint32_t k0 = 0u, k1 = 42u;
  const uint32_t k2 = k0 ^ k1 ^ 0x1BD11BDAu;
  x0 += k0; x1 += k1;
#define TF_R(r) { x0 += x1; x1 = (x1 << (r)) | (x1 >> (32 - (r))); x1 ^= x0; }
  TF_R(13) TF_R(15) TF_R(26) TF_R(6)
  x0 += k1; x1 += k2 + 1u;
  TF_R(17) TF_R(29) TF_R(16) TF_R(24)
  x0 += k2; x1 += k0 + 2u;
  TF_R(13) TF_R(15) TF_R(26) TF_R(6)
  x0 += k0; x1 += k1 + 3u;
  TF_R(17) TF_R(29) TF_R(16) TF_R(24)
  x0 += k1; x1 += k2 + 4u;
  TF_R(13) TF_R(15) TF_R(26) TF_R(6)
  x0 += k2; x1 += k0 + 5u;
#undef TF_R
  o0 = x0; o1 = x1;
}

__device__ __forceinline__ bf16x8 cvt8(const float* __restrict__ p) {
  float4 a = *(const float4*)p;
  float4 b = *(const float4*)(p + 4);
  bf16x8 r;
  r[0] = (__bf16)a.x; r[1] = (__bf16)a.y; r[2] = (__bf16)a.z; r[3] = (__bf16)a.w;
  r[4] = (__bf16)b.x; r[5] = (__bf16)b.y; r[6] = (__bf16)b.z; r[7] = (__bf16)b.w;
  return r;
}

__device__ __forceinline__ bf16x8 cvt8g(const float* p) {  // generic/LDS
  float4 a = *(const float4*)p;
  float4 b = *(const float4*)(p + 4);
  bf16x8 r;
  r[0] = (__bf16)a.x; r[1] = (__bf16)a.y; r[2] = (__bf16)a.z; r[3] = (__bf16)a.w;
  r[4] = (__bf16)b.x; r[5] = (__bf16)b.y; r[6] = (__bf16)b.z; r[7] = (__bf16)b.w;
  return r;
}

__device__ __forceinline__ void st4bf(__bf16* p, float4 v) {
  bf16x4 b;
  b[0] = (__bf16)v.x; b[1] = (__bf16)v.y; b[2] = (__bf16)v.z; b[3] = (__bf16)v.w;
  *(bf16x4*)p = b;
}

// ---------------- K1: per-block partial colsums + sumsq (overwrite) --------
__global__ __launch_bounds__(256) void k1_partial(const float* __restrict__ Pin,
                                                  const float* __restrict__ Ain,
                                                  float* __restrict__ ws) {
  __shared__ float scp[64], sca[64], ssq[2];
  int t = threadIdx.x, b = blockIdx.x;
  if (t < 64) { scp[t] = 0.f; sca[t] = 0.f; }
  if (t < 2) ssq[t] = 0.f;
  __syncthreads();
  const float4* P4 = (const float4*)Pin;
  const float4* A4 = (const float4*)Ain;
  float sp = 0.f, sa = 0.f;
  float cp0 = 0, cp1 = 0, cp2 = 0, cp3 = 0, ca0 = 0, ca1 = 0, ca2 = 0, ca3 = 0;
  int base = b * 512 + t;
#pragma unroll
  for (int k = 0; k < 2; ++k) {
    float4 p = P4[base + k * 256], a = A4[base + k * 256];
    sp += p.x * p.x + p.y * p.y + p.z * p.z + p.w * p.w;
    sa += a.x * a.x + a.y * a.y + a.z * a.z + a.w * a.w;
    cp0 += p.x; cp1 += p.y; cp2 += p.z; cp3 += p.w;
    ca0 += a.x; ca1 += a.y; ca2 += a.z; ca3 += a.w;
  }
  int c0 = (t * 4) & 63;
  atomicAdd(&scp[c0 + 0], cp0); atomicAdd(&scp[c0 + 1], cp1);
  atomicAdd(&scp[c0 + 2], cp2); atomicAdd(&scp[c0 + 3], cp3);
  atomicAdd(&sca[c0 + 0], ca0); atomicAdd(&sca[c0 + 1], ca1);
  atomicAdd(&sca[c0 + 2], ca2); atomicAdd(&sca[c0 + 3], ca3);
  for (int off = 32; off; off >>= 1) {
    sp += __shfl_down(sp, off);
    sa += __shfl_down(sa, off);
  }
  if ((t & 63) == 0) { atomicAdd(&ssq[0], sp); atomicAdd(&ssq[1], sa); }
  __syncthreads();
  float* dst = ws + WS_PART + b * 130;
  if (t < 64) { dst[2 + t] = scp[t]; dst[66 + t] = sca[t]; }
  if (t == 0) { dst[0] = ssq[0]; dst[1] = ssq[1]; }
}

// ---------------- K2a: split-K partial k_g --------------------------------
__global__ __launch_bounds__(256) void k2a_kgpart(const float* __restrict__ Wsflat,
                                                  const float* __restrict__ Wkw,
                                                  float* __restrict__ ws) {
  __shared__ float wkT[64][65];   // [j][o]
  __shared__ float wsT[64][17];   // [j][g]
  int t = threadIdx.x, b = blockIdx.x;
  int c0 = b * 64;
  for (int idx = t; idx < 1024; idx += 256) {
    int o = idx >> 4, c4 = idx & 15;
    float4 v = *(const float4*)(Wkw + o * 4096 + c0 + c4 * 4);
    wkT[c4 * 4 + 0][o] = v.x; wkT[c4 * 4 + 1][o] = v.y;
    wkT[c4 * 4 + 2][o] = v.z; wkT[c4 * 4 + 3][o] = v.w;
  }
  {
    int g = t >> 4, c4 = t & 15;
    float4 v = *(const float4*)(Wsflat + g * 4096 + c0 + c4 * 4);
    wsT[c4 * 4 + 0][g] = v.x; wsT[c4 * 4 + 1][g] = v.y;
    wsT[c4 * 4 + 2][g] = v.z; wsT[c4 * 4 + 3][g] = v.w;
  }
  __syncthreads();
  int o = t & 63, g0 = (t >> 6) * 4;
  float a0 = 0.f, a1 = 0.f, a2 = 0.f, a3 = 0.f;
#pragma unroll 8
  for (int j = 0; j < 64; ++j) {
    float wk = wkT[j][o];
    a0 += wk * wsT[j][g0 + 0];
    a1 += wk * wsT[j][g0 + 1];
    a2 += wk * wsT[j][g0 + 2];
    a3 += wk * wsT[j][g0 + 3];
  }
  float* dst = ws + WS_KGP + b * 1024;
  dst[(g0 + 0) * 64 + o] = a0; dst[(g0 + 1) * 64 + o] = a1;
  dst[(g0 + 2) * 64 + o] = a2; dst[(g0 + 3) * 64 + o] = a3;
}

// ---------------- K2b: reduce k_g partials (blocks 0-15) + k1 fold (16) ----
__global__ __launch_bounds__(256) void k2b_reduce(const float* __restrict__ Wkb,
                                                  float* __restrict__ ws) {
  int g = blockIdx.x, t = threadIdx.x;
  if (g == 16) {
    if (t < 130) {
      float s = 0.f;
#pragma unroll 8
      for (int b = 0; b < 256; ++b) s += ws[WS_PART + b * 130 + t];
      if (t == 0) ws[0] = s;
      else if (t == 1) ws[1] = s;
      else if (t < 66) ws[64 + (t - 2)] = s;
      else ws[128 + (t - 66)] = s;
    }
    return;
  }
  __shared__ float red[4][64];
  int o = t & 63, bq = t >> 6;
  float s = 0.f;
#pragma unroll
  for (int b = bq * 16; b < bq * 16 + 16; ++b)
    s += ws[WS_KGP + b * 1024 + g * 64 + o];
  red[bq][o] = s;
  __syncthreads();
  if (bq == 0)
    ws[WS_KG + g * 64 + o] = red[0][o] + red[1][o] + red[2][o] + red[3][o] + Wkb[o];
}

// ---------------- K34: per-node pipeline + propagated einsum (fused) -------
__global__ __launch_bounds__(256) void k34_fused(
    const float* __restrict__ z, const float* __restrict__ Pref,
    const float* __restrict__ Aref,
    const float* __restrict__ Wind_w, const float* __restrict__ Wind_b,
    const float* __restrict__ Wgate_w, const float* __restrict__ Wgate_b,
    const float* __restrict__ Wsys_w, const float* __restrict__ Wsys_b,
    const float* __restrict__ Ws,
    const float* __restrict__ ws, float* __restrict__ out_s,
    __bf16* __restrict__ PTF) {
  int t = threadIdx.x, wv = t >> 6, lane = t & 63;
  int lg = lane >> 4, lm = lane & 15;
  int n0 = blockIdx.x * 32;
  int nb = n0 + wv * 8;
  __shared__ float qs[4][16][68];
  __shared__ float dpa[4][2][16];
  __shared__ float al_lds[32][16];
  {
    int nl = lane >> 3, qt = lane & 7;
    const float4* pr4 = (const float4*)(Pref + (nb + nl) * 64 + qt * 8);
    const float4* ar4 = (const float4*)(Aref + (nb + nl) * 64 + qt * 8);
    const float4* mp4 = (const float4*)(ws + 64 + qt * 8);
    const float4* ma4 = (const float4*)(ws + 128 + qt * 8);
    float s1p = 0, s2p = 0, s1a = 0, s2a = 0;
#pragma unroll
    for (int j = 0; j < 2; ++j) {
      float4 p = pr4[j], a = ar4[j], mp = mp4[j], ma = ma4[j];
      s1p += p.x * mp.x + p.y * mp.y + p.z * mp.z + p.w * mp.w;
      s2p += p.x * p.x + p.y * p.y + p.z * p.z + p.w * p.w;
      s1a += a.x * ma.x + a.y * ma.y + a.z * ma.z + a.w * ma.w;
      s2a += a.x * a.x + a.y * a.y + a.z * a.z + a.w * a.w;
    }
    s1p += __shfl_xor(s1p, 1); s1p += __shfl_xor(s1p, 2); s1p += __shfl_xor(s1p, 4);
    s2p += __shfl_xor(s2p, 1); s2p += __shfl_xor(s2p, 2); s2p += __shfl_xor(s2p, 4);
    s1a += __shfl_xor(s1a, 1); s1a += __shfl_xor(s1a, 2); s1a += __shfl_xor(s1a, 4);
    s2a += __shfl_xor(s2a, 1); s2a += __shfl_xor(s2a, 2); s2a += __shfl_xor(s2a, 4);
    float m2P = ws[0] * (1.0f / 524288.0f);
    float m2A = ws[1] * (1.0f / 524288.0f);
    float dP = m2P - s1p * (2.0f / (64.0f * 8192.0f)) + s2p * (1.0f / 64.0f);
    float dA = m2A - s1a * (2.0f / (64.0f * 8192.0f)) + s2a * (1.0f / 64.0f);
    if (qt == 0) { dpa[wv][0][nl] = dP; dpa[wv][1][nl] = dA; }
    if (qt == 1) { dpa[wv][0][8 + nl] = 0.f; dpa[wv][1][8 + nl] = 0.f; }
  }
  int zrow = nb + lm; if (zrow > 8191) zrow = 8191;
  bf16x8 az[2];
#pragma unroll
  for (int h = 0; h < 2; ++h)
    az[h] = cvt8(z + zrow * 64 + h * 32 + lg * 8);
  f32x4 accg[4], acci[4];
#pragma unroll
  for (int ii = 0; ii < 4; ++ii) {
    f32x4 cg = {0.f, 0.f, 0.f, 0.f}, ci = {0.f, 0.f, 0.f, 0.f};
#pragma unroll
    for (int h = 0; h < 2; ++h) {
      bf16x8 bg = cvt8(Wgate_w + (ii * 16 + lm) * 64 + h * 32 + lg * 8);
      bf16x8 bi = cvt8(Wind_w + (ii * 16 + lm) * 64 + h * 32 + lg * 8);
      cg = __builtin_amdgcn_mfma_f32_16x16x32_bf16(az[h], bg, cg, 0, 0, 0);
      ci = __builtin_amdgcn_mfma_f32_16x16x32_bf16(az[h], bi, ci, 0, 0, 0);
    }
    accg[ii] = cg; acci[ii] = ci;
  }
  __syncthreads();
#pragma unroll
  for (int ii = 0; ii < 4; ++ii) {
    int o = ii * 16 + lm;
    float bg = Wgate_b[o], bi = Wind_b[o], bs = Wsys_b[o];
    float w0 = Wsys_w[o * 2], w1 = Wsys_w[o * 2 + 1];
#pragma unroll
    for (int r = 0; r < 4; ++r) {
      int node = lg * 4 + r;
      float dP = dpa[wv][0][node], dA = dpa[wv][1][node];
      float gate = 1.0f / (1.0f + expf(-(accg[ii][r] + bg)));
      float sys = dA * w0 + dP * w1 + bs;
      qs[wv][node][o] = acci[ii][r] + bi + gate * sys;
    }
  }
  __syncthreads();
  {
    bf16x8 aq[2], bq[2];
#pragma unroll
    for (int h = 0; h < 2; ++h) {
      aq[h] = cvt8g(&qs[wv][lm][h * 32 + lg * 8]);
      bq[h] = cvt8g(ws + WS_KG + lm * 64 + h * 32 + lg * 8);
    }
    f32x4 accs = {0.f, 0.f, 0.f, 0.f};
    accs = __builtin_amdgcn_mfma_f32_16x16x32_bf16(aq[0], bq[0], accs, 0, 0, 0);
    accs = __builtin_amdgcn_mfma_f32_16x16x32_bf16(aq[1], bq[1], accs, 0, 0, 0);
    if (lg < 2) {
#pragma unroll
      for (int r = 0; r < 4; ++r) {
        int n = nb + lg * 4 + r;
        float sv = accs[r] * 0.125f;
        uint32_t idx = (uint32_t)(n * 16 + lm);
        uint32_t r0_, r1_;
        threefry2x32(0u, idx, r0_, r1_);
        uint32_t bits = r0_ ^ r1_;
        float u = __uint_as_float((bits >> 9) | 0x3f800000u) - 1.0f;
        float gum = -logf(-logf(u + 1e-10f) + 1e-10f);
        float tv = sv + gum;  // TAU = 1
        float mx = tv;
        mx = fmaxf(mx, __shfl_xor(mx, 1)); mx = fmaxf(mx, __shfl_xor(mx, 2));
        mx = fmaxf(mx, __shfl_xor(mx, 4)); mx = fmaxf(mx, __shfl_xor(mx, 8));
        float e = expf(tv - mx);
        float se = e;
        se += __shfl_xor(se, 1); se += __shfl_xor(se, 2);
        se += __shfl_xor(se, 4); se += __shfl_xor(se, 8);
        out_s[n * 16 + lm] = sv;
        al_lds[wv * 8 + lg * 4 + r][lm] = e / se;
      }
    }
  }
  __syncthreads();
  bf16x8 af[2][2];
#pragma unroll
  for (int m = 0; m < 2; ++m)
#pragma unroll
    for (int h = 0; h < 2; ++h)
      af[m][h] = cvt8(z + (n0 + m * 16 + lm) * 64 + h * 32 + lg * 8);
  int i0 = wv * 16;
  f32x4 prop[2] = {{0.f, 0.f, 0.f, 0.f}, {0.f, 0.f, 0.f, 0.f}};
  for (int g = 0; g < 16; ++g) {
    bf16x8 bf[2];
#pragma unroll
    for (int h = 0; h < 2; ++h)
      bf[h] = cvt8(Ws + g * 4096 + (i0 + lm) * 64 + h * 32 + lg * 8);
#pragma unroll
    for (int m = 0; m < 2; ++m) {
      f32x4 tf = {0.f, 0.f, 0.f, 0.f};
      tf = __builtin_amdgcn_mfma_f32_16x16x32_bf16(af[m][0], bf[0], tf, 0, 0, 0);
      tf = __builtin_amdgcn_mfma_f32_16x16x32_bf16(af[m][1], bf[1], tf, 0, 0, 0);
#pragma unroll
      for (int r = 0; r < 4; ++r)
        prop[m][r] += al_lds[m * 16 + lg * 4 + r][g] * tf[r];
    }
  }
  // PTF write: flat = blk*2048 + wv*512 + (m*2+(lg>>1))*128 + lm*8 + (lg&1)*4 + r
#pragma unroll
  for (int m = 0; m < 2; ++m) {
    float4 v = {prop[m][0], prop[m][1], prop[m][2], prop[m][3]};
    st4bf(PTF + blockIdx.x * 2048 + wv * 512 + (m * 2 + (lg >> 1)) * 128 +
              lm * 8 + (lg & 1) * 4, v);
  }
}

// ---------------- K5: h = leaky_relu(R @ propagated), 8 big K-tiles --------
// 512 blocks x 512 thr; 16 rows/block; 8 K-tiles of 1024 cols (was 16x512).
// The compiler's mandatory vmcnt(0) drain before each s_barrier costs a
// fixed ~0.5us refill per phase; halving the barrier count halves that tax
// while per-phase BW work doubles. LDS [2][16][1044] bf16 = 66.8 KB
// (stride 522 dw = 10 mod 32: all 16 rows in distinct banks, conflict-free).
__global__ __launch_bounds__(512) void k5_gemm(const float* __restrict__ R,
                                               const __bf16* __restrict__ PTF,
                                               float* __restrict__ out) {
  __shared__ __bf16 lds[2][16][1044];   // 66.8 KB
  int t = threadIdx.x, wv = t >> 6, lane = t & 63;
  int lg = lane >> 4, lm = lane & 15;
  int row0 = blockIdx.x * 16;
  int srow[8], scol[8];
#pragma unroll
  for (int r = 0; r < 8; ++r) {
    int idx = r * 512 + t;       // 4096 float4 = 16 rows x 256
    srow[r] = idx >> 8;
    scol[r] = (idx & 255) * 4;
  }
  const float* Rb = R + (size_t)row0 * 8192;
  f32x4 acc[4];
#pragma unroll
  for (int ii = 0; ii < 4; ++ii) acc[ii] = {0.f, 0.f, 0.f, 0.f};
  float4 stg[8];
#pragma unroll
  for (int r = 0; r < 8; ++r)
    stg[r] = *(const float4*)(Rb + (size_t)srow[r] * 8192 + scol[r]);
#pragma unroll
  for (int r = 0; r < 8; ++r)
    st4bf(&lds[0][srow[r]][scol[r]], stg[r]);
  __syncthreads();
  for (int tile = 0; tile < 8; ++tile) {
    int cur = tile & 1;
    if (tile < 7) {
#pragma unroll
      for (int r = 0; r < 8; ++r)
        stg[r] = *(const float4*)(Rb + (size_t)srow[r] * 8192 + (tile + 1) * 1024 + scol[r]);
    }
#pragma unroll
    for (int ks = 0; ks < 4; ++ks) {
      int kc = wv * 128 + ks * 32 + lg * 8;
      bf16x8 a = *(const bf16x8*)&lds[cur][lm][kc];
      int kb = tile * 32 + wv * 4 + ks;
#pragma unroll
      for (int ii = 0; ii < 4; ++ii) {
        bf16x8 b = *(const bf16x8*)(PTF + kb * 2048 + ii * 512 + lane * 8);
        acc[ii] = __builtin_amdgcn_mfma_f32_16x16x32_bf16(a, b, acc[ii], 0, 0, 0);
      }
    }
    if (tile < 7) {
#pragma unroll
      for (int r = 0; r < 8; ++r)
        st4bf(&lds[cur ^ 1][srow[r]][scol[r]], stg[r]);
    }
    __syncthreads();
  }
  // epilogue: reduce 8 waves' partial K-sums in LDS (reuse buffers; 32 KB)
  float* red = (float*)&lds[0][0][0];
#pragma unroll
  for (int ii = 0; ii < 4; ++ii)
#pragma unroll
    for (int r = 0; r < 4; ++r)
      red[wv * 1024 + (lg * 4 + r) * 64 + ii * 16 + lm] = acc[ii][r];
  __syncthreads();
  for (int e = t; e < 1024; e += 512) {
    int rr = e >> 6, cc = e & 63;
    float v = 0.f;
#pragma unroll
    for (int w = 0; w < 8; ++w) v += red[w * 1024 + rr * 64 + cc];
    v = v > 0.f ? v : 0.01f * v;
    out[(row0 + rr) * 64 + cc] = v;
  }
}

extern "C" void kernel_launch(void* const* d_in, const int* in_sizes, int n_in,
                              void* d_out, int out_size, void* d_ws, size_t ws_size,
                              hipStream_t stream) {
  const float* z      = (const float*)d_in[0];
  const float* Pref   = (const float*)d_in[1];
  const float* Pin    = (const float*)d_in[2];
  const float* Aref   = (const float*)d_in[3];
  const float* Ain    = (const float*)d_in[4];
  const float* R      = (const float*)d_in[5];
  const float* Wind_w = (const float*)d_in[6];
  const float* Wind_b = (const float*)d_in[7];
  const float* Wgate_w= (const float*)d_in[8];
  const float* Wgate_b= (const float*)d_in[9];
  const float* Wsys_w = (const float*)d_in[10];
  const float* Wsys_b = (const float*)d_in[11];
  const float* Ws     = (const float*)d_in[12];
  const float* Wkw    = (const float*)d_in[13];
  const float* Wkb    = (const float*)d_in[14];
  float* out = (float*)d_out;
  float* ws  = (float*)d_ws;
  __bf16* PTF = (__bf16*)((char*)d_ws + WS_PT_BYTE);

  k1_partial<<<256, 256, 0, stream>>>(Pin, Ain, ws);
  k2a_kgpart<<<64, 256, 0, stream>>>(Ws, Wkw, ws);
  k2b_reduce<<<17, 256, 0, stream>>>(Wkb, ws);
  k34_fused<<<256, 256, 0, stream>>>(z, Pref, Aref, Wind_w, Wind_b, Wgate_w,
                                     Wgate_b, Wsys_w, Wsys_b, Ws, ws,
                                     out + 524288, PTF);
  k5_gemm<<<512, 512, 0, stream>>>(R, PTF, out);
}